// Round 1
// baseline (156.670 us; speedup 1.0000x reference)
//
#include <hip/hip_runtime.h>

#define FDIM 512
#define HALF 256

__global__ __launch_bounds__(1024, 1)
void rvsoftmax_fused(const float* __restrict__ mu,
                     const float* __restrict__ Sigma,
                     float* __restrict__ p_out,
                     float* __restrict__ S_out) {
    const int b = blockIdx.x;
    const int t = threadIdx.x;
    const int w = t >> 6;   // wave id 0..15
    const int l = t & 63;   // lane id

    __shared__ __align__(16) float p_lds[FDIM];
    __shared__ __align__(16) float r_lds[FDIM];
    __shared__ __align__(16) float c_lds[FDIM];
    __shared__ __align__(16) float c_stage[16][FDIM];
    __shared__ float red[16];
    __shared__ float sc[2];

    // ---------------- Phase 0: softmax over mu[b,:] ----------------
    float x = (t < FDIM) ? mu[(size_t)b * FDIM + t] : -__builtin_inff();
    float m = x;
    #pragma unroll
    for (int off = 32; off >= 1; off >>= 1) m = fmaxf(m, __shfl_xor(m, off));
    if (l == 0) red[w] = m;
    __syncthreads();                       // B1
    if (t == 0) {
        float mm = red[0];
        for (int j = 1; j < 16; ++j) mm = fmaxf(mm, red[j]);
        sc[0] = mm;
    }
    __syncthreads();                       // B2
    const float mx = sc[0];
    float e = (t < FDIM) ? __expf(x - mx) : 0.f;
    float ssum = e;
    #pragma unroll
    for (int off = 32; off >= 1; off >>= 1) ssum += __shfl_xor(ssum, off);
    if (l == 0) red[w] = ssum;             // safe: red reads finished before B2
    __syncthreads();                       // B3
    if (t == 0) {
        float tt = 0.f;
        for (int j = 0; j < 16; ++j) tt += red[j];
        sc[0] = tt;                        // all mx reads happened before B3
    }
    __syncthreads();                       // B4
    const float inv = 1.0f / sc[0];
    if (t < FDIM) {
        float pv = e * inv;
        p_lds[t] = pv;
        p_out[(size_t)b * FDIM + t] = pv;
    }
    __syncthreads();                       // B5

    // ---------------- Phase 1: r = Sigma p, c = p^T Sigma ----------------
    const float* Sb = Sigma + (size_t)b * FDIM * FDIM;
    const float4 p0 = *(const float4*)&p_lds[4 * l];
    const float4 p1 = *(const float4*)&p_lds[HALF + 4 * l];
    float4 c0 = make_float4(0.f, 0.f, 0.f, 0.f);
    float4 c1 = make_float4(0.f, 0.f, 0.f, 0.f);

    for (int j = 0; j < 32; ++j) {
        const int i = j * 16 + w;
        const float* row = Sb + (size_t)i * FDIM;
        const float4 a0 = *(const float4*)&row[4 * l];
        const float4 a1 = *(const float4*)&row[HALF + 4 * l];
        const float pi = p_lds[i];
        float dot = a0.x * p0.x + a0.y * p0.y + a0.z * p0.z + a0.w * p0.w
                  + a1.x * p1.x + a1.y * p1.y + a1.z * p1.z + a1.w * p1.w;
        #pragma unroll
        for (int off = 32; off >= 1; off >>= 1) dot += __shfl_xor(dot, off);
        if (l == 0) r_lds[i] = dot;
        c0.x += pi * a0.x; c0.y += pi * a0.y; c0.z += pi * a0.z; c0.w += pi * a0.w;
        c1.x += pi * a1.x; c1.y += pi * a1.y; c1.z += pi * a1.z; c1.w += pi * a1.w;
    }
    *(float4*)&c_stage[w][4 * l] = c0;
    *(float4*)&c_stage[w][HALF + 4 * l] = c1;
    __syncthreads();                       // B6

    if (t < FDIM) {
        float cc = 0.f;
        #pragma unroll
        for (int j = 0; j < 16; ++j) cc += c_stage[j][t];
        c_lds[t] = cc;
    }
    __syncthreads();                       // B7

    // s = p . r
    float sv = (t < FDIM) ? p_lds[t] * r_lds[t] : 0.f;
    #pragma unroll
    for (int off = 32; off >= 1; off >>= 1) sv += __shfl_xor(sv, off);
    if (l == 0) red[w] = sv;
    __syncthreads();                       // B8
    if (t == 0) {
        float tt = 0.f;
        for (int j = 0; j < 16; ++j) tt += red[j];
        sc[1] = tt;
    }
    __syncthreads();                       // B9
    const float s = sc[1];

    // ---------------- Phase 2: out = p_i p_k (Sigma - r_i - c_k + s) ----
    // Reverse row order: the most recently read rows are re-read first,
    // maximizing L2/L3 hit rate on the second pass.
    const float4 cc0 = *(const float4*)&c_lds[4 * l];
    const float4 cc1 = *(const float4*)&c_lds[HALF + 4 * l];
    float* Ob = S_out + (size_t)b * FDIM * FDIM;

    for (int j = 31; j >= 0; --j) {
        const int i = j * 16 + w;
        const float* row = Sb + (size_t)i * FDIM;
        float* orow = Ob + (size_t)i * FDIM;
        const float4 a0 = *(const float4*)&row[4 * l];
        const float4 a1 = *(const float4*)&row[HALF + 4 * l];
        const float pi = p_lds[i];
        const float f = s - r_lds[i];
        float4 o0, o1;
        o0.x = pi * p0.x * (a0.x + (f - cc0.x));
        o0.y = pi * p0.y * (a0.y + (f - cc0.y));
        o0.z = pi * p0.z * (a0.z + (f - cc0.z));
        o0.w = pi * p0.w * (a0.w + (f - cc0.w));
        o1.x = pi * p1.x * (a1.x + (f - cc1.x));
        o1.y = pi * p1.y * (a1.y + (f - cc1.y));
        o1.z = pi * p1.z * (a1.z + (f - cc1.z));
        o1.w = pi * p1.w * (a1.w + (f - cc1.w));
        *(float4*)&orow[4 * l] = o0;
        *(float4*)&orow[HALF + 4 * l] = o1;
    }
}

extern "C" void kernel_launch(void* const* d_in, const int* in_sizes, int n_in,
                              void* d_out, int out_size, void* d_ws, size_t ws_size,
                              hipStream_t stream) {
    const float* mu    = (const float*)d_in[0];
    const float* Sigma = (const float*)d_in[1];
    float* p_out = (float*)d_out;
    float* S_out = (float*)d_out + (size_t)256 * 512;   // p first, then Sigma_out
    hipLaunchKernelGGL(rvsoftmax_fused, dim3(256), dim3(1024), 0, stream,
                       mu, Sigma, p_out, S_out);
}

// Round 2
// 145.066 us; speedup vs baseline: 1.0800x; 1.0800x over previous
//
#include <hip/hip_runtime.h>

#define FDIM 512
#define CHUNK 32          // rows per staged chunk (64 KB)
#define NCH 16            // 512 / 32

#define WAITVM4() asm volatile("s_waitcnt vmcnt(4)" ::: "memory")
#define WAITVM0() asm volatile("s_waitcnt vmcnt(0)" ::: "memory")
#define WAITLGKM0() asm volatile("s_waitcnt lgkmcnt(0)" ::: "memory")
#define BAR() __builtin_amdgcn_s_barrier()

__device__ __forceinline__ void gld_lds16(const float* g, float* l) {
    __builtin_amdgcn_global_load_lds(
        (const __attribute__((address_space(1))) void*)g,
        (__attribute__((address_space(3))) void*)l, 16, 0, 0);
}

// Wave w stages its 2 rows (4 KB contiguous) of chunk ch into buf.
// 64 lanes x 16 B = 1 KB per instruction; 4 instructions per wave.
__device__ __forceinline__ void stage_chunk(const float* Sb, int ch, float* buf,
                                            int w, int l) {
    const float* g = Sb + (size_t)(ch * CHUNK + w * 2) * FDIM + l * 4;
    float* d = buf + (w * 2) * FDIM;            // wave-uniform LDS base
    gld_lds16(g,       d);
    gld_lds16(g + 256, d + 256);
    gld_lds16(g + 512, d + 512);
    gld_lds16(g + 768, d + 768);
}

__global__ __launch_bounds__(1024, 1)
void rvsoftmax_fused(const float* __restrict__ mu,
                     const float* __restrict__ Sigma,
                     float* __restrict__ p_out,
                     float* __restrict__ S_out) {
    const int b = blockIdx.x;
    const int t = threadIdx.x;
    const int w = t >> 6;   // wave 0..15
    const int l = t & 63;   // lane 0..63

    __shared__ __align__(16) float bufA[CHUNK * FDIM];   // 64 KB
    __shared__ __align__(16) float bufB[CHUNK * FDIM];   // 64 KB
    __shared__ __align__(16) float p_lds[FDIM];
    __shared__ __align__(16) float r_lds[FDIM];
    __shared__ __align__(16) float c_lds[FDIM];
    __shared__ float red[16];
    __shared__ float sc[2];

    const float* Sb = Sigma + (size_t)b * FDIM * FDIM;

    // Prefetch chunk 0 immediately (overlaps with softmax latency).
    stage_chunk(Sb, 0, bufA, w, l);

    // ---------------- Phase 0: softmax over mu[b,:] ----------------
    float x = (t < FDIM) ? mu[(size_t)b * FDIM + t] : -__builtin_inff();
    float m = x;
    #pragma unroll
    for (int off = 32; off >= 1; off >>= 1) m = fmaxf(m, __shfl_xor(m, off));
    if (l == 0) red[w] = m;
    __syncthreads();
    if (t == 0) {
        float mm = red[0];
        for (int j = 1; j < 16; ++j) mm = fmaxf(mm, red[j]);
        sc[0] = mm;
    }
    __syncthreads();
    const float mx = sc[0];
    float e = (t < FDIM) ? __expf(x - mx) : 0.f;
    float ssum = e;
    #pragma unroll
    for (int off = 32; off >= 1; off >>= 1) ssum += __shfl_xor(ssum, off);
    if (l == 0) red[w] = ssum;
    __syncthreads();
    if (t == 0) {
        float tt = 0.f;
        for (int j = 0; j < 16; ++j) tt += red[j];
        sc[0] = tt;
    }
    __syncthreads();
    const float inv = 1.0f / sc[0];
    if (t < FDIM) {
        float pv = e * inv;
        p_lds[t] = pv;
        p_out[(size_t)b * FDIM + t] = pv;
    }
    __syncthreads();

    const float4 p0 = *(const float4*)&p_lds[4 * l];
    const float4 p1 = *(const float4*)&p_lds[256 + 4 * l];

    // ---------------- Pass 1: r = Sigma p, partial c = p^T Sigma --------
    float4 c0 = make_float4(0.f, 0.f, 0.f, 0.f);
    float4 c1 = make_float4(0.f, 0.f, 0.f, 0.f);

    for (int ch = 0; ch < NCH; ++ch) {
        float* cur = (ch & 1) ? bufB : bufA;
        float* nxt = (ch & 1) ? bufA : bufB;
        if (ch + 1 < NCH) {
            stage_chunk(Sb, ch + 1, nxt, w, l);
            WAITVM4();               // current chunk's loads landed (mine)
        } else {
            WAITVM0();
        }
        BAR();                        // all waves' current-chunk loads landed

        #pragma unroll
        for (int q = 0; q < 2; ++q) {
            const int i = ch * CHUNK + w * 2 + q;
            const float* row = cur + (w * 2 + q) * FDIM;
            const float4 a0 = *(const float4*)&row[4 * l];
            const float4 a1 = *(const float4*)&row[256 + 4 * l];
            const float pi = p_lds[i];
            float dot = a0.x * p0.x + a0.y * p0.y + a0.z * p0.z + a0.w * p0.w
                      + a1.x * p1.x + a1.y * p1.y + a1.z * p1.z + a1.w * p1.w;
            #pragma unroll
            for (int off = 32; off >= 1; off >>= 1) dot += __shfl_xor(dot, off);
            if (l == 0) r_lds[i] = dot;
            c0.x += pi * a0.x; c0.y += pi * a0.y; c0.z += pi * a0.z; c0.w += pi * a0.w;
            c1.x += pi * a1.x; c1.y += pi * a1.y; c1.z += pi * a1.z; c1.w += pi * a1.w;
        }
        WAITLGKM0();                  // my LDS reads/writes retired
        BAR();                        // buf free for overwrite next iteration
    }

    // ---------------- Mid: reduce c partials (staged in bufA), s --------
    // bufA is free (last compute used bufB... both drained by final BAR).
    *(float4*)&bufA[w * FDIM + 4 * l] = c0;
    *(float4*)&bufA[w * FDIM + 256 + 4 * l] = c1;
    __syncthreads();
    if (t < FDIM) {
        float cc = 0.f;
        #pragma unroll
        for (int j = 0; j < 16; ++j) cc += bufA[j * FDIM + t];
        c_lds[t] = cc;
    }
    float sv = (t < FDIM) ? p_lds[t] * r_lds[t] : 0.f;
    #pragma unroll
    for (int off = 32; off >= 1; off >>= 1) sv += __shfl_xor(sv, off);
    if (l == 0) red[w] = sv;
    __syncthreads();
    if (t == 0) {
        float tt = 0.f;
        for (int j = 0; j < 16; ++j) tt += red[j];
        sc[1] = tt;
    }
    __syncthreads();
    const float s = sc[1];
    const float4 cc0 = *(const float4*)&c_lds[4 * l];
    const float4 cc1 = *(const float4*)&c_lds[256 + 4 * l];

    // ---------------- Pass 2: out = p_i p_k (Sigma - r_i - c_k + s) -----
    // Reverse chunk order for cache locality on the re-read.
    float* Ob = S_out + (size_t)b * FDIM * FDIM;

    stage_chunk(Sb, NCH - 1, bufA, w, l);       // prologue (bufA reads done)
    for (int it = 0; it < NCH; ++it) {
        const int ch = NCH - 1 - it;
        float* cur = (it & 1) ? bufB : bufA;
        float* nxt = (it & 1) ? bufA : bufB;
        if (it + 1 < NCH) stage_chunk(Sb, ch - 1, nxt, w, l);
        WAITVM4();                    // current chunk landed; old stores drained
        BAR();

        #pragma unroll
        for (int q = 0; q < 2; ++q) {
            const int i = ch * CHUNK + w * 2 + q;
            const float* row = cur + (w * 2 + q) * FDIM;
            const float4 a0 = *(const float4*)&row[4 * l];
            const float4 a1 = *(const float4*)&row[256 + 4 * l];
            const float pi = p_lds[i];
            const float f = s - r_lds[i];
            float4 o0, o1;
            o0.x = pi * p0.x * (a0.x + (f - cc0.x));
            o0.y = pi * p0.y * (a0.y + (f - cc0.y));
            o0.z = pi * p0.z * (a0.z + (f - cc0.z));
            o0.w = pi * p0.w * (a0.w + (f - cc0.w));
            o1.x = pi * p1.x * (a1.x + (f - cc1.x));
            o1.y = pi * p1.y * (a1.y + (f - cc1.y));
            o1.z = pi * p1.z * (a1.z + (f - cc1.z));
            o1.w = pi * p1.w * (a1.w + (f - cc1.w));
            float* orow = Ob + (size_t)i * FDIM;
            *(float4*)&orow[4 * l] = o0;
            *(float4*)&orow[256 + 4 * l] = o1;
        }
        WAITLGKM0();
        BAR();
    }
}

extern "C" void kernel_launch(void* const* d_in, const int* in_sizes, int n_in,
                              void* d_out, int out_size, void* d_ws, size_t ws_size,
                              hipStream_t stream) {
    const float* mu    = (const float*)d_in[0];
    const float* Sigma = (const float*)d_in[1];
    float* p_out = (float*)d_out;
    float* S_out = (float*)d_out + (size_t)256 * 512;
    hipLaunchKernelGGL(rvsoftmax_fused, dim3(256), dim3(1024), 0, stream,
                       mu, Sigma, p_out, S_out);
}